// Round 5
// baseline (7499.765 us; speedup 1.0000x reference)
//
#include <hip/hip_runtime.h>
#include <hip/hip_bf16.h>
#include <hip/hip_fp16.h>

typedef unsigned short u16;
typedef unsigned int u32;
typedef __attribute__((ext_vector_type(4))) float f32x4;
typedef __attribute__((ext_vector_type(8))) _Float16 f16x8;

#define MFMAH(a, b, c) __builtin_amdgcn_mfma_f32_16x16x32_f16((a), (b), (c), 0, 0, 0)

// LDS-drain-only barrier: does NOT drain vmcnt (keeps register gx prefetch
// in flight; compiler inserts vmcnt before actual register uses).
#define BAR() asm volatile("s_waitcnt lgkmcnt(0)\ns_barrier" ::: "memory")

__device__ __forceinline__ float bflo(u32 u) { return __uint_as_float(u << 16); }
__device__ __forceinline__ float bfhi(u32 u) { return __uint_as_float(u & 0xffff0000u); }
__device__ __forceinline__ float bf1(u16 u) { return __uint_as_float(((u32)u) << 16); }
__device__ __forceinline__ u16 f2bf(float f) {
    __hip_bfloat16 b = __float2bfloat16(f);
    return __builtin_bit_cast(u16, b);
}
__device__ __forceinline__ u16 f2h(float f) { return __builtin_bit_cast(u16, (_Float16)f); }
__device__ __forceinline__ u32 pk2h(float a, float b) {
    return (u32)f2h(a) | ((u32)f2h(b) << 16);
}
__device__ __forceinline__ float fexp2(float x) { return __builtin_amdgcn_exp2f(x); }
__device__ __forceinline__ float frcp(float x) { return __builtin_amdgcn_rcpf(x); }

__device__ __forceinline__ void cvt8(uint4 u, f32x4* lo, f32x4* hi) {
    f16x8 h = __builtin_bit_cast(f16x8, u);
    (*lo)[0] = (float)h[0]; (*lo)[1] = (float)h[1];
    (*lo)[2] = (float)h[2]; (*lo)[3] = (float)h[3];
    (*hi)[0] = (float)h[4]; (*hi)[1] = (float)h[5];
    (*hi)[2] = (float)h[6]; (*hi)[3] = (float)h[7];
}

// ---------------------------------------------------------------------------
// Wave-uniform dtype sniff: 1 = fp32 inputs, 0 = bf16.
// ---------------------------------------------------------------------------
__device__ __forceinline__ int sniff_fp32(const void* Wr) {
    const uint4* p = (const uint4*)Wr;
    uint4 v = p[threadIdx.x & 15];
    u32 a[4] = {v.x, v.y, v.z, v.w};
    float m = 0.f;
#pragma unroll
    for (int i = 0; i < 4; ++i) {
        float lo = fabsf(bflo(a[i])), hi = fabsf(bfhi(a[i]));
        if (!(lo < 1e30f)) lo = 1e30f;
        if (!(hi < 1e30f)) hi = 1e30f;
        m = fmaxf(m, fmaxf(lo, hi));
    }
#pragma unroll
    for (int off = 32; off; off >>= 1) m = fmaxf(m, __shfl_xor(m, off, 64));
    return m > 100.f ? 1 : 0;
}

__device__ __forceinline__ float load1f(const void* base, size_t idx, int f32) {
    return f32 ? ((const float*)base)[idx] : bf1(((const u16*)base)[idx]);
}

// ---------------------------------------------------------------------------
// One-shot weight convert to f16 in ws, PRE-SCALED:
//   W_r/W_z recurrent half (cols 256..511) *= -log2(e)
//   W_h recurrent half *= 2*log2(e)
// ---------------------------------------------------------------------------
__global__ void wconv(const void* __restrict__ Wr, const void* __restrict__ Wz,
                      const void* __restrict__ Wh, const void* __restrict__ Wfc,
                      u16* __restrict__ wf16)
{
    const int f32 = sniff_fp32(Wr);
    const int gid = blockIdx.x * 256 + threadIdx.x;
    const int e = gid * 4;
    const void* src;
    int off;
    float sc = 1.f;
    if (e < 131072)      { src = Wr;  off = e; }
    else if (e < 262144) { src = Wz;  off = e - 131072; }
    else if (e < 393216) { src = Wh;  off = e - 262144; }
    else                 { src = Wfc; off = e - 393216; }
    if (e < 393216 && (off & 511) >= 256)
        sc = (e < 262144) ? -1.442695041f : 2.885390082f;
    float4 v;
    if (f32) {
        v = *(const float4*)((const float*)src + off);
    } else {
        uint2 u = *(const uint2*)((const u16*)src + off);
        v.x = bflo(u.x); v.y = bfhi(u.x); v.z = bflo(u.y); v.w = bfhi(u.y);
    }
    uint2 o;
    o.x = pk2h(v.x * sc, v.y * sc);
    o.y = pk2h(v.z * sc, v.w * sc);
    *(uint2*)(wf16 + e) = o;
}

// ---------------------------------------------------------------------------
// Precompute gx = (x . W_g[:, :256]^T + b_g) * scale_g, f16.
// Output layout for the scan's DIRECT-TO-REGISTER loads, per step-slice:
//   [blk(4)][wave(4)][chunk c(6)][lane(64)][8 halfs]   (12288 halfs/step-blk)
// chunk c holds 12-tile index T = c*8+j >> 2 (T: r0..3, z0..3, h0..3),
// j&3 = batch row within lane's quad. Each scan load instr (1 chunk) is a
// perfectly coalesced 1 KB read.
// ---------------------------------------------------------------------------
__global__ __launch_bounds__(256, 2) void gru_pre(
    const void* __restrict__ x, const u16* __restrict__ wf16,
    const void* __restrict__ br, const void* __restrict__ bz, const void* __restrict__ bh,
    u16* __restrict__ gxc, int s0, int lgSc, const void* __restrict__ Wsniff)
{
    const int f32 = sniff_fp32(Wsniff);
    const int tid = threadIdx.x;
    const int R0 = blockIdx.x * 64;
    const int msk = (1 << lgSc) - 1;

    __shared__ __align__(16) _Float16 As[64][264];   // f16, +8 pad

    {
        const int i = tid >> 2;
        const int kq = (tid & 3) * 64;
        const int m = R0 + i;
        const int b = m >> lgSc;
        const int sl = m & msk;
        const size_t xbase = ((size_t)(b * 2048 + s0 + sl)) * 256 + kq;
        u16* dst = (u16*)&As[i][kq];
        if (f32) {
            const float4* p = (const float4*)((const float*)x + xbase);
#pragma unroll
            for (int j = 0; j < 8; ++j) {
                float4 v0 = p[2 * j], v1 = p[2 * j + 1];
                uint4 o;
                o.x = pk2h(v0.x, v0.y);
                o.y = pk2h(v0.z, v0.w);
                o.z = pk2h(v1.x, v1.y);
                o.w = pk2h(v1.z, v1.w);
                *(uint4*)(dst + j * 8) = o;
            }
        } else {
            const uint4* p = (const uint4*)((const u16*)x + xbase);
#pragma unroll
            for (int j = 0; j < 8; ++j) {
                uint4 v = p[j];
                uint4 o;
                o.x = pk2h(bflo(v.x), bfhi(v.x));
                o.y = pk2h(bflo(v.y), bfhi(v.y));
                o.z = pk2h(bflo(v.z), bfhi(v.z));
                o.w = pk2h(bflo(v.w), bfhi(v.w));
                *(uint4*)(dst + j * 8) = o;
            }
        }
    }
    __syncthreads();

    const int wv = tid >> 6;
    const int lane = tid & 63;
    const int q = lane >> 4, l16 = lane & 15;

    for (int j = 0; j < 3; ++j) {
        const int gi = wv * 3 + j;            // 0..11
        const int g = gi >> 2;
        const int col0 = (gi & 3) * 64;
        const void* bias = (g == 0) ? br : ((g == 1) ? bz : bh);
        const float cg = (g < 2) ? -1.442695041f : 2.885390082f;
        const size_t wbase = (size_t)(g * 256 + col0 + l16) * 512 + q * 8;

        f32x4 acc[4][4];
#pragma unroll
        for (int mt = 0; mt < 4; ++mt)
#pragma unroll
            for (int nt = 0; nt < 4; ++nt) acc[mt][nt] = (f32x4){0, 0, 0, 0};

#pragma unroll
        for (int k0 = 0; k0 < 256; k0 += 32) {
            f16x8 bfr[4];
#pragma unroll
            for (int nt = 0; nt < 4; ++nt)
                bfr[nt] = *(const f16x8*)(wf16 + wbase + (size_t)nt * 8192 + k0);
#pragma unroll
            for (int mt = 0; mt < 4; ++mt) {
                f16x8 af = *(const f16x8*)&As[mt * 16 + l16][k0 + q * 8];
#pragma unroll
                for (int nt = 0; nt < 4; ++nt)
                    acc[mt][nt] = MFMAH(af, bfr[nt], acc[mt][nt]);
            }
        }
#pragma unroll
        for (int nt = 0; nt < 4; ++nt) {
            const int col = col0 + nt * 16 + l16;
            const float bv = load1f(bias, col, f32);
            const int Tg = (col >> 4) & 3;
            const size_t cpart = (size_t)(col >> 6) * 3072
                + (size_t)(g * 2 + (Tg >> 1)) * 512
                + (size_t)(col & 15) * 8 + (Tg & 1) * 4;
#pragma unroll
            for (int mt = 0; mt < 4; ++mt)
#pragma unroll
                for (int r = 0; r < 4; ++r) {
                    const int m = R0 + mt * 16 + q * 4 + r;
                    const int b = m >> lgSc;
                    const int sl = m & msk;
                    const int bb = b & 15;
                    const size_t hidx = (size_t)sl * 49152 + (size_t)(b >> 4) * 12288
                        + cpart + (size_t)(bb >> 2) * 128 + (bb & 3);
                    gxc[hidx] = f2h((acc[mt][nt][r] + bv) * cg);
                }
        }
    }
}

// ---------------------------------------------------------------------------
// Sequential scan v5: register-resident weights (the real fix).
// 4 blocks x 256 threads (4 waves), __launch_bounds__(256,1) -> 512-reg/wave
// budget (1 wave/SIMD). Each wave owns 64 cols: W_r,W_z,W_h recurrent halves
// = 384 regs held in the unified VGPR/AGPR file for the whole kernel -- the
// rounds-2..4 kernels could not hold them (256-reg cap) and re-read 384 KB
// from L2 every step, which was the hidden 2900 cyc/step.
//  - gx loaded DIRECTLY to registers (prefetched one phase ahead, compiler-
//    tracked vmcnt; no LDS staging at all).
//  - h / r*h exchanged via LDS in MFMA-fragment-linear layout with a
//    bijective bank swizzle: A-reads are contiguous 1KB ds_read_b128 (0
//    conflicts); scalar state writes spread across all 8 bank quads.
// ---------------------------------------------------------------------------
__global__ __launch_bounds__(256, 1) void gru_scan(
    const u16* __restrict__ gxc,   // [Sc][4][12288] f16 chunk layout
    const u16* __restrict__ wf16,  // [3][256][512] f16, recurrent half scaled
    float* __restrict__ h_state,
    u16* __restrict__ hs,          // [64][Sc][256] f16
    void* __restrict__ outbase,    // h_last at element 33554432
    const void* __restrict__ Wsniff,
    int Sc, int first, int last)
{
    const int f32o = sniff_fp32(Wsniff);
    const int tid = threadIdx.x;
    const int wv = tid >> 6, lane = tid & 63;
    const int q = lane >> 4, l16 = lane & 15;
    const int b0 = blockIdx.x * 16;

    // state buffers, fragment-linear + swizzled:
    // value A[row=b][k=col] lives at half-index
    //   (col>>3)*128 + ((b ^ p ^ sg)*8) + (col&7)
    // with p = (b>>3)*5 folded via writer consts, sg = ((col>>3)&1)*3.
    __shared__ __align__(16) _Float16 h_lin[4096];
    __shared__ __align__(16) _Float16 rh_lin[4096];

    // per-thread swizzle constants
    const int plx = (l16 ^ ((l16 >> 3) * 5)) ^ ((q & 1) * 3);
    const int aoff = q * 128 + plx * 8;               // A-read: + kk*512
    const int wsw = ((q >> 1) * 5) ^ ((l16 >> 3) * 3);
    const int cbase = wv * 8 + (l16 >> 3);            // col>>3 = cbase + t*2
    const int l7 = l16 & 7;

    // ---- persistent weights: 3 gates x 4 tiles x 8 k-blocks = 384 regs ----
    f16x8 wr[4][8], wz[4][8], wh[4][8];
#pragma unroll
    for (int t = 0; t < 4; ++t) {
        const int col = wv * 64 + t * 16 + l16;
        const size_t rb0 = (size_t)(col) * 512 + 256 + q * 8;
        const size_t rb1 = (size_t)(256 + col) * 512 + 256 + q * 8;
        const size_t rb2 = (size_t)(512 + col) * 512 + 256 + q * 8;
#pragma unroll
        for (int kk = 0; kk < 8; ++kk) {
            wr[t][kk] = *(const f16x8*)(wf16 + rb0 + kk * 32);
            wz[t][kk] = *(const f16x8*)(wf16 + rb1 + kk * 32);
            wh[t][kk] = *(const f16x8*)(wf16 + rb2 + kk * 32);
        }
    }

    // ---- init h (registers + swizzled LDS) ----
    float h_old[4][4];
#pragma unroll
    for (int t = 0; t < 4; ++t) {
        const int col = wv * 64 + t * 16 + l16;
        const int cb = (cbase + t * 2) * 128 + l7;
#pragma unroll
        for (int r = 0; r < 4; ++r) {
            const int b = q * 4 + r;
            float h0 = first ? 0.f : h_state[(size_t)(b0 + b) * 256 + col];
            h_old[t][r] = h0;
            h_lin[cb + ((b ^ wsw) * 8)] = (_Float16)h0;
        }
    }
    BAR();

    // ---- gx pointers (each wave loads only its own 6 chunks) ----
    const char* gp = (const char*)gxc + (size_t)blockIdx.x * 24576
                     + (size_t)wv * 6144 + ((size_t)lane << 4);
    uint4 pr01 = *(const uint4*)(gp);
    uint4 pr23 = *(const uint4*)(gp + 1024);
    uint4 pz01 = *(const uint4*)(gp + 2048);
    uint4 pz23 = *(const uint4*)(gp + 3072);

    // ---- hs-stream constants (linear LDS chunk -> (batch,col) decode) ----
    const int n0 = tid * 2;
    const int C0 = n0 >> 4;
    const int sg0 = (C0 & 1) * 3;
    int u0 = (n0 & 15) ^ sg0;       u0 ^= (u0 >> 3) * 5;
    int u1 = ((n0 + 1) & 15) ^ sg0; u1 ^= (u1 >> 3) * 5;
    u16* hsp0 = hs + (size_t)(b0 + u0) * Sc * 256 + C0 * 8;
    u16* hsp1 = hs + (size_t)(b0 + u1) * Sc * 256 + C0 * 8;

    for (int s = 0; s < Sc; ++s) {
        const char* gps = gp + (size_t)s * 98304;
        // issue h-gate gx loads for this step (consumed in ph2)
        uint4 ph01 = *(const uint4*)(gps + 4096);
        uint4 ph23 = *(const uint4*)(gps + 5120);

        // stream h(s-1) to hs (reads h_lin, which ph1 never writes)
        {
            const int slot = (s > 0) ? (s - 1) : 0;
            uint4 v0 = *(const uint4*)&h_lin[n0 * 8];
            uint4 v1 = *(const uint4*)&h_lin[n0 * 8 + 8];
            *(uint4*)(hsp0 + (size_t)slot * 256) = v0;
            *(uint4*)(hsp1 + (size_t)slot * 256) = v1;
        }

        // ---- ph1: r and z, C initialized from gx ----
        f32x4 accr[4], accz[4];
        cvt8(pr01, &accr[0], &accr[1]);
        cvt8(pr23, &accr[2], &accr[3]);
        cvt8(pz01, &accz[0], &accz[1]);
        cvt8(pz23, &accz[2], &accz[3]);
#pragma unroll
        for (int kk = 0; kk < 8; ++kk) {
            f16x8 a = *(const f16x8*)&h_lin[kk * 512 + aoff];
            accr[0] = MFMAH(a, wr[0][kk], accr[0]);
            accr[1] = MFMAH(a, wr[1][kk], accr[1]);
            accr[2] = MFMAH(a, wr[2][kk], accr[2]);
            accr[3] = MFMAH(a, wr[3][kk], accr[3]);
            accz[0] = MFMAH(a, wz[0][kk], accz[0]);
            accz[1] = MFMAH(a, wz[1][kk], accz[1]);
            accz[2] = MFMAH(a, wz[2][kk], accz[2]);
            accz[3] = MFMAH(a, wz[3][kk], accz[3]);
        }
        // r epilogue (z deferred into ph2's shadow)
#pragma unroll
        for (int t = 0; t < 4; ++t) {
            const int cb = (cbase + t * 2) * 128 + l7;
#pragma unroll
            for (int r = 0; r < 4; ++r) {
                float sg = frcp(1.f + fexp2(accr[t][r]));
                rh_lin[cb + (((q * 4 + r) ^ wsw) * 8)] =
                    (_Float16)(sg * h_old[t][r]);
            }
        }
        BAR();

        // ---- ph2: prefetch next step's r/z gx, then h~ + update ----
        {
            int sn = s + 1; if (sn > Sc - 1) sn = Sc - 1;
            const char* gpn = gp + (size_t)sn * 98304;
            pr01 = *(const uint4*)(gpn);
            pr23 = *(const uint4*)(gpn + 1024);
            pz01 = *(const uint4*)(gpn + 2048);
            pz23 = *(const uint4*)(gpn + 3072);
        }
        f32x4 acch[4];
        cvt8(ph01, &acch[0], &acch[1]);
        cvt8(ph23, &acch[2], &acch[3]);
#pragma unroll
        for (int kk = 0; kk < 8; ++kk) {
            f16x8 a = *(const f16x8*)&rh_lin[kk * 512 + aoff];
            acch[0] = MFMAH(a, wh[0][kk], acch[0]);
            acch[1] = MFMAH(a, wh[1][kk], acch[1]);
            acch[2] = MFMAH(a, wh[2][kk], acch[2]);
            acch[3] = MFMAH(a, wh[3][kk], acch[3]);
        }
#pragma unroll
        for (int t = 0; t < 4; ++t) {
            const int col = wv * 64 + t * 16 + l16;
            const int cb = (cbase + t * 2) * 128 + l7;
#pragma unroll
            for (int r = 0; r < 4; ++r) {
                const int b = q * 4 + r;
                float zz = frcp(1.f + fexp2(accz[t][r]));
                float e = fexp2(acch[t][r]);
                float ht = fmaf(-2.f, frcp(e + 1.f), 1.f);
                float hold = h_old[t][r];
                float hn = fmaf(zz, ht - hold, hold);
                h_old[t][r] = hn;
                h_lin[cb + ((b ^ wsw) * 8)] = (_Float16)hn;
                if (s == Sc - 1) {
                    h_state[(size_t)(b0 + b) * 256 + col] = hn;
                    if (last) {
                        const size_t li = (size_t)33554432 + (size_t)(b0 + b) * 256 + col;
                        if (f32o) ((float*)outbase)[li] = hn;
                        else      ((u16*)outbase)[li] = f2bf(hn);
                    }
                }
            }
        }
        BAR();
    }
    // final hs row: h(Sc-1)
    {
        uint4 v0 = *(const uint4*)&h_lin[n0 * 8];
        uint4 v1 = *(const uint4*)&h_lin[n0 * 8 + 8];
        *(uint4*)(hsp0 + (size_t)(Sc - 1) * 256) = v0;
        *(uint4*)(hsp1 + (size_t)(Sc - 1) * 256) = v1;
    }
}

// ---------------------------------------------------------------------------
// Output projection: reads hs (f16, ws) and wfc16 (f16, ws), writes d_out.
// ---------------------------------------------------------------------------
__global__ __launch_bounds__(256) void gru_proj(
    const u16* __restrict__ wfc16, const void* __restrict__ bfc,
    const void* __restrict__ Wsniff, const u16* __restrict__ hs,
    void* __restrict__ outb, int s0, int lgSc)
{
    const int f32 = sniff_fp32(Wsniff);
    const int lane = threadIdx.x & 63;
    const int wave = threadIdx.x >> 6;
    const int q = lane >> 4, l16 = lane & 15;
    const int msk = (1 << lgSc) - 1;
    const int m0 = blockIdx.x * 64 + wave * 16;
    const size_t aidx = (size_t)(m0 + l16) * 256 + q * 8;
    const size_t widx = (size_t)l16 * 256 + q * 8;
    f32x4 acc[16];
#pragma unroll
    for (int t = 0; t < 16; ++t) acc[t] = (f32x4){0, 0, 0, 0};
#pragma unroll 2
    for (int k0 = 0; k0 < 256; k0 += 32) {
        f16x8 af = *(const f16x8*)(hs + aidx + k0);
#pragma unroll
        for (int t = 0; t < 16; ++t) {
            f16x8 bfg = *(const f16x8*)(wfc16 + widx + (size_t)t * 4096 + k0);
            acc[t] = MFMAH(af, bfg, acc[t]);
        }
    }
#pragma unroll
    for (int t = 0; t < 16; ++t) {
        const int col = t * 16 + l16;
        const float bv = load1f(bfc, col, f32);
#pragma unroll
        for (int r = 0; r < 4; ++r) {
            const int m = m0 + q * 4 + r;
            const int b = m >> lgSc;
            const int sl = m & msk;
            const size_t oidx = ((size_t)b * 2048 + s0 + sl) * 256 + col;
            float v = acc[t][r] + bv;
            if (f32) ((float*)outb)[oidx] = v;
            else     ((u16*)outb)[oidx] = f2bf(v);
        }
    }
}

// ---------------------------------------------------------------------------
extern "C" void kernel_launch(void* const* d_in, const int* in_sizes, int n_in,
                              void* d_out, int out_size, void* d_ws, size_t ws_size,
                              hipStream_t stream) {
    (void)in_sizes; (void)n_in; (void)out_size;
    const void* x   = d_in[0];
    const void* Wr  = d_in[1];
    const void* br  = d_in[2];
    const void* Wz  = d_in[3];
    const void* bz  = d_in[4];
    const void* Wh  = d_in[5];
    const void* bh  = d_in[6];
    const void* Wfc = d_in[7];
    const void* bfc = d_in[8];

    float* h_state = (float*)d_ws;                        // 64*256 fp32 = 64KB
    u16*   wf16    = (u16*)((char*)d_ws + 65536);         // 458752 halfs

    int lgSc = 11;
    while (lgSc > 0 &&
           (size_t)1048576 + ((size_t)131072 << lgSc) > ws_size) --lgSc;
    const int Sc = 1 << lgSc;
    u16* gxc = (u16*)((char*)d_ws + 1048576);
    u16* hs  = (u16*)((char*)d_ws + 1048576 + (size_t)Sc * 98304);

    wconv<<<448, 256, 0, stream>>>(Wr, Wz, Wh, Wfc, wf16);

    for (int s0 = 0; s0 < 2048; s0 += Sc) {
        gru_pre<<<Sc, 256, 0, stream>>>(x, wf16, br, bz, bh, gxc, s0, lgSc, Wr);
        gru_scan<<<4, 256, 0, stream>>>(gxc, wf16, h_state, hs, d_out, Wr,
                                        Sc, (s0 == 0) ? 1 : 0,
                                        (s0 + Sc == 2048) ? 1 : 0);
        gru_proj<<<Sc, 256, 0, stream>>>(wf16 + 393216, bfc, Wr, hs, d_out,
                                         s0, lgSc);
    }
}

// Round 6
// 6538.664 us; speedup vs baseline: 1.1470x; 1.1470x over previous
//
#include <hip/hip_runtime.h>
#include <hip/hip_bf16.h>
#include <hip/hip_fp16.h>

typedef unsigned short u16;
typedef unsigned int u32;
typedef __attribute__((ext_vector_type(4))) float f32x4;
typedef __attribute__((ext_vector_type(8))) _Float16 f16x8;

#define MFMAH(a, b, c) __builtin_amdgcn_mfma_f32_16x16x32_f16((a), (b), (c), 0, 0, 0)

// LDS-drain-only barrier (does not force vmcnt(0); global gx loads and h
// stores are register-tracked by compiler-inserted waits).
#define BAR() asm volatile("s_waitcnt lgkmcnt(0)\ns_barrier" ::: "memory")

__device__ __forceinline__ float bflo(u32 u) { return __uint_as_float(u << 16); }
__device__ __forceinline__ float bfhi(u32 u) { return __uint_as_float(u & 0xffff0000u); }
__device__ __forceinline__ float bf1(u16 u) { return __uint_as_float(((u32)u) << 16); }
__device__ __forceinline__ u16 f2bf(float f) {
    __hip_bfloat16 b = __float2bfloat16(f);
    return __builtin_bit_cast(u16, b);
}
__device__ __forceinline__ u16 f2h(float f) { return __builtin_bit_cast(u16, (_Float16)f); }
__device__ __forceinline__ u32 pk2h(float a, float b) {
    return (u32)f2h(a) | ((u32)f2h(b) << 16);
}
__device__ __forceinline__ float fexp2(float x) { return __builtin_amdgcn_exp2f(x); }
__device__ __forceinline__ float frcp(float x) { return __builtin_amdgcn_rcpf(x); }

// ---------------------------------------------------------------------------
// Wave-uniform dtype sniff: 1 = fp32 inputs, 0 = bf16.
// ---------------------------------------------------------------------------
__device__ __forceinline__ int sniff_fp32(const void* Wr) {
    const uint4* p = (const uint4*)Wr;
    uint4 v = p[threadIdx.x & 15];
    u32 a[4] = {v.x, v.y, v.z, v.w};
    float m = 0.f;
#pragma unroll
    for (int i = 0; i < 4; ++i) {
        float lo = fabsf(bflo(a[i])), hi = fabsf(bfhi(a[i]));
        if (!(lo < 1e30f)) lo = 1e30f;
        if (!(hi < 1e30f)) hi = 1e30f;
        m = fmaxf(m, fmaxf(lo, hi));
    }
#pragma unroll
    for (int off = 32; off; off >>= 1) m = fmaxf(m, __shfl_xor(m, off, 64));
    return m > 100.f ? 1 : 0;
}

__device__ __forceinline__ float load1f(const void* base, size_t idx, int f32) {
    return f32 ? ((const float*)base)[idx] : bf1(((const u16*)base)[idx]);
}

// ---------------------------------------------------------------------------
// One-shot weight convert to f16 in ws, PRE-SCALED:
//   W_r/W_z recurrent half (cols 256..511) *= -log2(e)
//   W_h recurrent half *= 2*log2(e)
// ---------------------------------------------------------------------------
__global__ void wconv(const void* __restrict__ Wr, const void* __restrict__ Wz,
                      const void* __restrict__ Wh, const void* __restrict__ Wfc,
                      u16* __restrict__ wf16)
{
    const int f32 = sniff_fp32(Wr);
    const int gid = blockIdx.x * 256 + threadIdx.x;
    const int e = gid * 4;
    const void* src;
    int off;
    float sc = 1.f;
    if (e < 131072)      { src = Wr;  off = e; }
    else if (e < 262144) { src = Wz;  off = e - 131072; }
    else if (e < 393216) { src = Wh;  off = e - 262144; }
    else                 { src = Wfc; off = e - 393216; }
    if (e < 393216 && (off & 511) >= 256)
        sc = (e < 262144) ? -1.442695041f : 2.885390082f;
    float4 v;
    if (f32) {
        v = *(const float4*)((const float*)src + off);
    } else {
        uint2 u = *(const uint2*)((const u16*)src + off);
        v.x = bflo(u.x); v.y = bfhi(u.x); v.z = bflo(u.y); v.w = bfhi(u.y);
    }
    uint2 o;
    o.x = pk2h(v.x * sc, v.y * sc);
    o.y = pk2h(v.z * sc, v.w * sc);
    *(uint2*)(wf16 + e) = o;
}

// ---------------------------------------------------------------------------
// Precompute gx = (x . W_g[:, :256]^T + b_g) * scale_g, f16.
// Layout matches the scan's per-wave direct-to-register uint4 loads:
//   hidx = sl*49152 + (b>>4)*12288 + (col>>5)*1536 + g*512
//        + ((b&15)>>2)*128 + (col&15)*8 + ((col>>4)&1)*4 + (b&3)
// so scan wave wv's lane (q,l16) reads 8 halfs [t*4+r] contiguously per gate,
// each (wave,gate) read = one coalesced 1 KB instruction.
// ---------------------------------------------------------------------------
__global__ __launch_bounds__(256, 2) void gru_pre(
    const void* __restrict__ x, const u16* __restrict__ wf16,
    const void* __restrict__ br, const void* __restrict__ bz, const void* __restrict__ bh,
    u16* __restrict__ gxc, int s0, int lgSc, const void* __restrict__ Wsniff)
{
    const int f32 = sniff_fp32(Wsniff);
    const int tid = threadIdx.x;
    const int R0 = blockIdx.x * 64;
    const int msk = (1 << lgSc) - 1;

    __shared__ __align__(16) _Float16 As[64][264];   // f16, +8 pad

    {
        const int i = tid >> 2;
        const int kq = (tid & 3) * 64;
        const int m = R0 + i;
        const int b = m >> lgSc;
        const int sl = m & msk;
        const size_t xbase = ((size_t)(b * 2048 + s0 + sl)) * 256 + kq;
        u16* dst = (u16*)&As[i][kq];
        if (f32) {
            const float4* p = (const float4*)((const float*)x + xbase);
#pragma unroll
            for (int j = 0; j < 8; ++j) {
                float4 v0 = p[2 * j], v1 = p[2 * j + 1];
                uint4 o;
                o.x = pk2h(v0.x, v0.y);
                o.y = pk2h(v0.z, v0.w);
                o.z = pk2h(v1.x, v1.y);
                o.w = pk2h(v1.z, v1.w);
                *(uint4*)(dst + j * 8) = o;
            }
        } else {
            const uint4* p = (const uint4*)((const u16*)x + xbase);
#pragma unroll
            for (int j = 0; j < 8; ++j) {
                uint4 v = p[j];
                uint4 o;
                o.x = pk2h(bflo(v.x), bfhi(v.x));
                o.y = pk2h(bflo(v.y), bfhi(v.y));
                o.z = pk2h(bflo(v.z), bfhi(v.z));
                o.w = pk2h(bflo(v.w), bfhi(v.w));
                *(uint4*)(dst + j * 8) = o;
            }
        }
    }
    __syncthreads();

    const int wv = tid >> 6;
    const int lane = tid & 63;
    const int q = lane >> 4, l16 = lane & 15;

    for (int j = 0; j < 3; ++j) {
        const int gi = wv * 3 + j;            // 0..11
        const int g = gi >> 2;
        const int col0 = (gi & 3) * 64;
        const void* bias = (g == 0) ? br : ((g == 1) ? bz : bh);
        const float cg = (g < 2) ? -1.442695041f : 2.885390082f;
        const size_t wbase = (size_t)(g * 256 + col0 + l16) * 512 + q * 8;

        f32x4 acc[4][4];
#pragma unroll
        for (int mt = 0; mt < 4; ++mt)
#pragma unroll
            for (int nt = 0; nt < 4; ++nt) acc[mt][nt] = (f32x4){0, 0, 0, 0};

#pragma unroll
        for (int k0 = 0; k0 < 256; k0 += 32) {
            f16x8 bfr[4];
#pragma unroll
            for (int nt = 0; nt < 4; ++nt)
                bfr[nt] = *(const f16x8*)(wf16 + wbase + (size_t)nt * 8192 + k0);
#pragma unroll
            for (int mt = 0; mt < 4; ++mt) {
                f16x8 af = *(const f16x8*)&As[mt * 16 + l16][k0 + q * 8];
#pragma unroll
                for (int nt = 0; nt < 4; ++nt)
                    acc[mt][nt] = MFMAH(af, bfr[nt], acc[mt][nt]);
            }
        }
#pragma unroll
        for (int nt = 0; nt < 4; ++nt) {
            const int col = col0 + nt * 16 + l16;
            const float bv = load1f(bias, col, f32);
            const int c0 = (col >> 5) * 1536 + g * 512 + (col & 15) * 8
                           + ((col >> 4) & 1) * 4;
#pragma unroll
            for (int mt = 0; mt < 4; ++mt)
#pragma unroll
                for (int r = 0; r < 4; ++r) {
                    const int m = R0 + mt * 16 + q * 4 + r;
                    const int b = m >> lgSc;
                    const int sl = m & msk;
                    const size_t hidx = (size_t)sl * 49152 + (size_t)(b >> 4) * 12288
                        + (size_t)(c0 + ((b & 15) >> 2) * 128 + (b & 3));
                    gxc[hidx] = f2h((acc[mt][nt][r] + bv) * cg);
                }
        }
    }
}

// ---------------------------------------------------------------------------
// Sequential scan v6: weights-resident AND 2 waves/SIMD.
// 4 blocks x 512 threads. Each wave owns 32 cols x all 3 gates = 192 weight
// regs (the irreducible 1536/8); working set cut to ~60 so 2/SIMD (cap 256)
// finally fits: gx = 3 single-buffered uint4 register loads (C-initializers),
// A-frags streamed 1/kk, z-sigmoid in ph2's shadow, h streamed straight to
// d_out (no hs buffer). LDS = r5's verified conflict-free fragment swizzle.
// ---------------------------------------------------------------------------
__global__ __launch_bounds__(512, 2) void gru_scan(
    const u16* __restrict__ gxc,   // [Sc][4][12288] f16 (layout above)
    const u16* __restrict__ wf16,  // [3][256][512] f16, recurrent half scaled
    float* __restrict__ h_state,
    void* __restrict__ outbase,    // d_out; h rows in place, h_last @33554432
    const void* __restrict__ Wsniff,
    int s0, int Sc, int first, int last)
{
    const int f32o = sniff_fp32(Wsniff);
    const int tid = threadIdx.x;
    const int wv = tid >> 6, lane = tid & 63;
    const int q = lane >> 4, l16 = lane & 15;
    const int b0 = blockIdx.x * 16;

    __shared__ __align__(16) _Float16 h_lin[4096];
    __shared__ __align__(16) _Float16 rh_lin[4096];

    // swizzle constants (verified in r5): reader A-frag offset and writer slot
    const int plx = (l16 ^ ((l16 >> 3) * 5)) ^ ((q & 1) * 3);
    const int aoff = q * 128 + plx * 8;                 // + kk*512
    const int wsw = ((q >> 1) * 5) ^ ((l16 >> 3) * 3);
    const int cb2 = (wv * 4 + (l16 >> 3)) * 128 + (l16 & 7);  // + t*256

    // ---- persistent weights: [gate][tile t][kk] = 192 regs ----
    f16x8 w[3][2][8];
#pragma unroll
    for (int g = 0; g < 3; ++g)
#pragma unroll
        for (int t = 0; t < 2; ++t) {
            const size_t rowb =
                (size_t)(g * 256 + wv * 32 + t * 16 + l16) * 512 + 256 + q * 8;
#pragma unroll
            for (int kk = 0; kk < 8; ++kk)
                w[g][t][kk] = *(const f16x8*)(wf16 + rowb + kk * 32);
        }

    // ---- init h (f32 regs + swizzled f16 LDS) ----
    float h_old[2][4];
#pragma unroll
    for (int t = 0; t < 2; ++t) {
        const int col = wv * 32 + t * 16 + l16;
#pragma unroll
        for (int r = 0; r < 4; ++r) {
            const int b = q * 4 + r;
            float h0 = first ? 0.f : h_state[(size_t)(b0 + b) * 256 + col];
            h_old[t][r] = h0;
            h_lin[cb2 + t * 256 + (((b) ^ wsw) * 8)] = (_Float16)h0;
        }
    }
    BAR();

    // gx base for this wave's lane (halfs); kinds at +0 (r), +512 (z), +1024 (h)
    const u16* gq = gxc + (size_t)blockIdx.x * 12288 + wv * 1536 + q * 128 + l16 * 8;
    const size_t gstep = 49152;

    uint4 PR = *(const uint4*)(gq);
    uint4 PZ = *(const uint4*)(gq + 512);
    uint4 PH = *(const uint4*)(gq + 1024);

    for (int s = 0; s < Sc; ++s) {
        const int sn = (s + 1 < Sc) ? (s + 1) : (Sc - 1);
        const u16* gqn = gq + (size_t)sn * gstep;

        // ---- ph1: C-init from gx, reload PR/PZ for s+1, r+z MFMA ----
        f32x4 accr[2], accz[2];
        {
            f16x8 hr = __builtin_bit_cast(f16x8, PR);
            f16x8 hz = __builtin_bit_cast(f16x8, PZ);
#pragma unroll
            for (int t = 0; t < 2; ++t)
#pragma unroll
                for (int r = 0; r < 4; ++r) {
                    accr[t][r] = (float)hr[t * 4 + r];
                    accz[t][r] = (float)hz[t * 4 + r];
                }
        }
        PR = *(const uint4*)(gqn);
        PZ = *(const uint4*)(gqn + 512);
#pragma unroll
        for (int kk = 0; kk < 8; ++kk) {
            f16x8 a = *(const f16x8*)&h_lin[kk * 512 + aoff];
            accr[0] = MFMAH(a, w[0][0][kk], accr[0]);
            accr[1] = MFMAH(a, w[0][1][kk], accr[1]);
            accz[0] = MFMAH(a, w[1][0][kk], accz[0]);
            accz[1] = MFMAH(a, w[1][1][kk], accz[1]);
        }
        // r epilogue: rh -> LDS (z deferred past the barrier)
#pragma unroll
        for (int t = 0; t < 2; ++t)
#pragma unroll
            for (int r = 0; r < 4; ++r) {
                float sg = frcp(1.f + fexp2(accr[t][r]));
                rh_lin[cb2 + t * 256 + (((q * 4 + r) ^ wsw) * 8)] =
                    (_Float16)(sg * h_old[t][r]);
            }
        BAR();

        // ---- ph2: h~ MFMA (C from gx), z sigmoid in the shadow, update ----
        f32x4 acch[2];
        {
            f16x8 hh = __builtin_bit_cast(f16x8, PH);
#pragma unroll
            for (int t = 0; t < 2; ++t)
#pragma unroll
                for (int r = 0; r < 4; ++r) acch[t][r] = (float)hh[t * 4 + r];
        }
        PH = *(const uint4*)(gqn + 1024);
        float zz[2][4];
#pragma unroll
        for (int t = 0; t < 2; ++t)
#pragma unroll
            for (int r = 0; r < 4; ++r) zz[t][r] = frcp(1.f + fexp2(accz[t][r]));
#pragma unroll
        for (int kk = 0; kk < 8; ++kk) {
            f16x8 a = *(const f16x8*)&rh_lin[kk * 512 + aoff];
            acch[0] = MFMAH(a, w[2][0][kk], acch[0]);
            acch[1] = MFMAH(a, w[2][1][kk], acch[1]);
        }
#pragma unroll
        for (int t = 0; t < 2; ++t) {
            const int col = wv * 32 + t * 16 + l16;
#pragma unroll
            for (int r = 0; r < 4; ++r) {
                const int b = q * 4 + r;
                float e = fexp2(acch[t][r]);
                float ht = fmaf(-2.f, frcp(e + 1.f), 1.f);
                float hold = h_old[t][r];
                float hn = fmaf(zz[t][r], ht - hold, hold);
                h_old[t][r] = hn;
                h_lin[cb2 + t * 256 + ((b ^ wsw) * 8)] = (_Float16)hn;
                const size_t oidx =
                    ((size_t)(b0 + b) * 2048 + (s0 + s)) * 256 + col;
                if (f32o) ((float*)outbase)[oidx] = hn;
                else      ((u16*)outbase)[oidx] = f2bf(hn);
                if (s == Sc - 1) {
                    h_state[(size_t)(b0 + b) * 256 + col] = hn;
                    if (last) {
                        const size_t li = (size_t)33554432 + (size_t)(b0 + b) * 256 + col;
                        if (f32o) ((float*)outbase)[li] = hn;
                        else      ((u16*)outbase)[li] = f2bf(hn);
                    }
                }
            }
        }
        BAR();
    }
}

// ---------------------------------------------------------------------------
// Output projection IN-PLACE on d_out: each wave reads exactly the 16 h-rows
// it later overwrites (loads precede stores in program order; waves own
// disjoint rows) -> race-free. A converted f32/bf16 -> f16; W from wfc16.
// ---------------------------------------------------------------------------
__global__ __launch_bounds__(256) void gru_proj(
    const u16* __restrict__ wfc16, const void* __restrict__ bfc,
    const void* __restrict__ Wsniff, void* __restrict__ io,
    int s0, int lgSc)
{
    const int f32 = sniff_fp32(Wsniff);
    const int lane = threadIdx.x & 63;
    const int wave = threadIdx.x >> 6;
    const int q = lane >> 4, l16 = lane & 15;
    const int msk = (1 << lgSc) - 1;
    const int m0 = blockIdx.x * 64 + wave * 16;
    const int mA = m0 + l16;
    const size_t arow = ((size_t)(mA >> lgSc) * 2048 + s0 + (mA & msk)) * 256;
    const size_t widx = (size_t)l16 * 256 + q * 8;
    f32x4 acc[16];
#pragma unroll
    for (int t = 0; t < 16; ++t) acc[t] = (f32x4){0, 0, 0, 0};
#pragma unroll 2
    for (int k0 = 0; k0 < 256; k0 += 32) {
        f16x8 af;
        if (f32) {
            const float* ap = (const float*)io + arow + q * 8 + k0;
            float4 v0 = *(const float4*)ap, v1 = *(const float4*)(ap + 4);
            af[0] = (_Float16)v0.x; af[1] = (_Float16)v0.y;
            af[2] = (_Float16)v0.z; af[3] = (_Float16)v0.w;
            af[4] = (_Float16)v1.x; af[5] = (_Float16)v1.y;
            af[6] = (_Float16)v1.z; af[7] = (_Float16)v1.w;
        } else {
            uint4 v = *(const uint4*)((const u16*)io + arow + q * 8 + k0);
            af[0] = (_Float16)bflo(v.x); af[1] = (_Float16)bfhi(v.x);
            af[2] = (_Float16)bflo(v.y); af[3] = (_Float16)bfhi(v.y);
            af[4] = (_Float16)bflo(v.z); af[5] = (_Float16)bfhi(v.z);
            af[6] = (_Float16)bflo(v.w); af[7] = (_Float16)bfhi(v.w);
        }
#pragma unroll
        for (int t = 0; t < 16; ++t) {
            f16x8 bfg = *(const f16x8*)(wfc16 + widx + (size_t)t * 4096 + k0);
            acc[t] = MFMAH(af, bfg, acc[t]);
        }
    }
#pragma unroll
    for (int t = 0; t < 16; ++t) {
        const int col = t * 16 + l16;
        const float bv = load1f(bfc, col, f32);
#pragma unroll
        for (int r = 0; r < 4; ++r) {
            const int m = m0 + q * 4 + r;
            const size_t oidx =
                ((size_t)(m >> lgSc) * 2048 + s0 + (m & msk)) * 256 + col;
            float v = acc[t][r] + bv;
            if (f32) ((float*)io)[oidx] = v;
            else     ((u16*)io)[oidx] = f2bf(v);
        }
    }
}

// ---------------------------------------------------------------------------
// ws: [0,64K) h_state f32 | [64K,~960K) wf16 | [1M, 1M+Sc*96K) gxc f16.
// Per chunk: pre -> scan (h into d_out) -> proj (in-place).
// ---------------------------------------------------------------------------
extern "C" void kernel_launch(void* const* d_in, const int* in_sizes, int n_in,
                              void* d_out, int out_size, void* d_ws, size_t ws_size,
                              hipStream_t stream) {
    (void)in_sizes; (void)n_in; (void)out_size;
    const void* x   = d_in[0];
    const void* Wr  = d_in[1];
    const void* br  = d_in[2];
    const void* Wz  = d_in[3];
    const void* bz  = d_in[4];
    const void* Wh  = d_in[5];
    const void* bh  = d_in[6];
    const void* Wfc = d_in[7];
    const void* bfc = d_in[8];

    float* h_state = (float*)d_ws;                        // 64*256 fp32 = 64KB
    u16*   wf16    = (u16*)((char*)d_ws + 65536);         // 458752 halfs

    int lgSc = 11;
    while (lgSc > 0 &&
           (size_t)1048576 + ((size_t)98304 << lgSc) > ws_size) --lgSc;
    const int Sc = 1 << lgSc;
    u16* gxc = (u16*)((char*)d_ws + 1048576);

    wconv<<<448, 256, 0, stream>>>(Wr, Wz, Wh, Wfc, wf16);

    for (int s0 = 0; s0 < 2048; s0 += Sc) {
        gru_pre<<<Sc, 256, 0, stream>>>(x, wf16, br, bz, bh, gxc, s0, lgSc, Wr);
        gru_scan<<<4, 512, 0, stream>>>(gxc, wf16, h_state, d_out, Wr,
                                        s0, Sc, (s0 == 0) ? 1 : 0,
                                        (s0 + Sc == 2048) ? 1 : 0);
        gru_proj<<<Sc, 256, 0, stream>>>(wf16 + 393216, bfc, Wr, d_out,
                                         s0, lgSc);
    }
}